// Round 3
// baseline (11923.373 us; speedup 1.0000x reference)
//
#include <hip/hip_runtime.h>
#include <hip/hip_bf16.h>
#include <cmath>

typedef __bf16 bf16_t;
typedef __bf16 bf16x4 __attribute__((ext_vector_type(4)));
typedef __bf16 bf16x8 __attribute__((ext_vector_type(8)));
typedef float f32x4 __attribute__((ext_vector_type(4)));

typedef const __attribute__((address_space(1))) void gv_t;
typedef __attribute__((address_space(3))) void sv_t;

#define GLDS16(g, l) __builtin_amdgcn_global_load_lds((gv_t*)(g), (sv_t*)(l), 16, 0, 0)

// ---------------- GEMM: C = A @ B^T (+bias)(+epilogue) ----------------
// A: [4096, K] bf16 row-major ; B: [N, K] bf16 row-major (weights [out,in])
// bias: f32. EPI: 0 = store f32, no bias ; 1 = +bias, store f32 ;
//      2 = +bias, Cf[row*1024+col] += v (residual, N==1024) ;
//      3 = +bias, gelu, store bf16 ; 4 = +bias, store bf16
template <int EPI>
__global__ __launch_bounds__(256, 2) void gemm128(
    const bf16_t* __restrict__ A, const bf16_t* __restrict__ B,
    const float* __restrict__ bias, float* __restrict__ Cf,
    bf16_t* __restrict__ Cb, int N, int K)
{
    __shared__ __align__(16) bf16_t As[128 * 32];
    __shared__ __align__(16) bf16_t Bs[128 * 32];
    const int tid = threadIdx.x;
    const int bm = blockIdx.x, bn = blockIdx.y;
    const int wave = tid >> 6, lane = tid & 63;
    const int wr = (wave >> 1) << 6, wc = (wave & 1) << 6;
    const int lr = lane & 15, kq = (lane >> 4) << 3;

    f32x4 acc[4][4] = {};

    const bf16_t* gA = A + (size_t)(bm * 128 + (tid >> 2)) * K + (tid & 3) * 8;
    const bf16_t* gB = B + (size_t)(bn * 128 + (tid >> 2)) * K + (tid & 3) * 8;
    const bf16_t* gA2 = gA + (size_t)64 * K;
    const bf16_t* gB2 = gB + (size_t)64 * K;
    bf16_t* lA = As + tid * 8;
    bf16_t* lB = Bs + tid * 8;

    for (int k0 = 0; k0 < K; k0 += 32) {
        __syncthreads();
        GLDS16(gA + k0, lA);
        GLDS16(gA2 + k0, lA + 2048);
        GLDS16(gB + k0, lB);
        GLDS16(gB2 + k0, lB + 2048);
        __syncthreads();
        bf16x8 af[4], bfr[4];
#pragma unroll
        for (int i = 0; i < 4; i++)
            af[i] = *(const bf16x8*)(As + (wr + i * 16 + lr) * 32 + kq);
#pragma unroll
        for (int j = 0; j < 4; j++)
            bfr[j] = *(const bf16x8*)(Bs + (wc + j * 16 + lr) * 32 + kq);
#pragma unroll
        for (int i = 0; i < 4; i++)
#pragma unroll
            for (int j = 0; j < 4; j++)
                acc[i][j] = __builtin_amdgcn_mfma_f32_16x16x32_bf16(af[i], bfr[j], acc[i][j], 0, 0, 0);
    }

    const int row0 = bm * 128 + wr + ((lane >> 4) << 2);
    const int col0 = bn * 128 + wc + lr;
#pragma unroll
    for (int j = 0; j < 4; j++) {
        const int col = col0 + j * 16;
        float bv = 0.f;
        if constexpr (EPI != 0) bv = bias[col];
#pragma unroll
        for (int i = 0; i < 4; i++) {
#pragma unroll
            for (int r = 0; r < 4; r++) {
                const int row = row0 + i * 16 + r;
                float v = acc[i][j][r] + bv;
                if constexpr (EPI == 0 || EPI == 1) {
                    Cf[(size_t)row * N + col] = v;
                } else if constexpr (EPI == 2) {
                    Cf[(size_t)row * 1024 + col] += v;
                } else if constexpr (EPI == 3) {
                    float g = 0.5f * v * (1.f + tanhf(0.7978845608f * (v + 0.044715f * v * v * v)));
                    Cb[(size_t)row * N + col] = (bf16_t)g;
                } else {
                    Cb[(size_t)row * N + col] = (bf16_t)v;
                }
            }
        }
    }
}

// ---------------- per-layer weight convert f32 -> bf16 (4 tensors fused) ----------------
// sizes (f32 elements): qkv 3145728, proj 1048576, fc1 4194304, fc2 4194304
__global__ __launch_bounds__(256) void convw_k(
    const float* __restrict__ q, const float* __restrict__ p,
    const float* __restrict__ f1, const float* __restrict__ f2,
    bf16_t* __restrict__ oq, bf16_t* __restrict__ op,
    bf16_t* __restrict__ of1, bf16_t* __restrict__ of2)
{
    int idx = blockIdx.x * 256 + threadIdx.x;   // in float4 units; 3145728 total
    const float* src; bf16_t* dst; int off;
    if (idx < 786432)       { src = q;  dst = oq;  off = idx; }
    else if (idx < 1048576) { src = p;  dst = op;  off = idx - 786432; }
    else if (idx < 2097152) { src = f1; dst = of1; off = idx - 1048576; }
    else                    { src = f2; dst = of2; off = idx - 2097152; }
    float4 v = ((const float4*)src)[off];
    bf16x4 o; o[0] = (bf16_t)v.x; o[1] = (bf16_t)v.y; o[2] = (bf16_t)v.z; o[3] = (bf16_t)v.w;
    *(bf16x4*)(dst + (size_t)off * 4) = o;
}

// ---------------- generic f32 -> bf16 convert ----------------
__global__ __launch_bounds__(256) void cvt_k(const float* __restrict__ in, bf16_t* __restrict__ out)
{
    int idx = blockIdx.x * 256 + threadIdx.x;   // float4 units
    float4 v = ((const float4*)in)[idx];
    bf16x4 o; o[0] = (bf16_t)v.x; o[1] = (bf16_t)v.y; o[2] = (bf16_t)v.z; o[3] = (bf16_t)v.w;
    *(bf16x4*)(out + (size_t)idx * 4) = o;
}

// ---------------- SpatialMerger patch gather: x f32[4,16,64,64] -> patches bf16[4096,64] ----------------
__global__ __launch_bounds__(256) void patches_k(const float* __restrict__ x, bf16_t* __restrict__ out)
{
    int idx = blockIdx.x * 256 + threadIdx.x;  // 262144 total
    int cc = idx & 63, l = (idx >> 6) & 1023, n = idx >> 16;
    int c = cc >> 2, kh = (cc >> 1) & 1, kw = cc & 1;
    int hf = l >> 5, wf = l & 31;
    out[idx] = (bf16_t)x[(((n * 16 + c) * 64) + hf * 2 + kh) * 64 + wf * 2 + kw];
}

// ---------------- RMSNorm: tok f32 [4096,1024] -> bf16 ----------------
__global__ __launch_bounds__(256) void rmsnorm_k(const float* __restrict__ tok, bf16_t* __restrict__ out)
{
    int row = blockIdx.x, tid = threadIdx.x;
    float4 xv = ((const float4*)(tok + (size_t)row * 1024))[tid];
    float s = xv.x * xv.x + xv.y * xv.y + xv.z * xv.z + xv.w * xv.w;
#pragma unroll
    for (int off = 32; off > 0; off >>= 1) s += __shfl_down(s, off, 64);
    __shared__ float ws4[4];
    if ((tid & 63) == 0) ws4[tid >> 6] = s;
    __syncthreads();
    float sc = rsqrtf((ws4[0] + ws4[1] + ws4[2] + ws4[3]) * (1.f / 1024.f) + 1e-6f);
    bf16_t* o = out + (size_t)row * 1024 + tid * 4;
    bf16x4 ov;
    ov[0] = (bf16_t)(xv.x * sc); ov[1] = (bf16_t)(xv.y * sc);
    ov[2] = (bf16_t)(xv.z * sc); ov[3] = (bf16_t)(xv.w * sc);
    *(bf16x4*)o = ov;
}

// ---------------- 2D RoPE in-place on q,k inside qkv bf16 [4096,3072] ----------------
__global__ __launch_bounds__(256) void rope_k(bf16_t* __restrict__ qkv)
{
    int idx = blockIdx.x * 256 + threadIdx.x;  // 2097152 total
    int j = idx & 31, h = (idx >> 5) & 15, t = (idx >> 9) & 1023, n = idx >> 19;
    int b = j >> 4, jj = j & 15;
    float pos = (float)(b ? (t & 31) : (t >> 5));       // pos_w = t%32 ; pos_h = t/32
    float ang = pos * exp2f(-13.287712379549449f * (float)jj * (1.f / 16.f));  // 10000^(-jj/16)
    float sn, cs;
    sincosf(ang, &sn, &cs);
    bf16_t* qp = qkv + (size_t)(n * 1024 + t) * 3072 + h * 64 + b * 32 + jj;
    float q0 = (float)qp[0], q1 = (float)qp[16];
    qp[0]  = (bf16_t)(q0 * cs - q1 * sn);
    qp[16] = (bf16_t)(q1 * cs + q0 * sn);
    bf16_t* kp = qp + 1024;
    float k0 = (float)kp[0], k1 = (float)kp[16];
    kp[0]  = (bf16_t)(k0 * cs - k1 * sn);
    kp[16] = (bf16_t)(k1 * cs + k0 * sn);
}

// ---------------- Flash attention: one query per lane, 4-way key split per block ----------------
__global__ __launch_bounds__(256, 2) void attn_k(const bf16_t* __restrict__ qkv, bf16_t* __restrict__ obuf)
{
    __shared__ float sm[4][64];
    __shared__ float sl[4][64];
    __shared__ bf16_t so[4][64][65];   // padded: avoids full bank serialization
    const int tid = threadIdx.x, wave = tid >> 6, lane = tid & 63;
    const int blk = blockIdx.x;        // 1024 = n(4) * h(16) * qblk(16)
    const int qb = blk & 15, h = (blk >> 4) & 15, n = blk >> 8;
    const int t = qb * 64 + lane;
    const bf16_t* qrow = qkv + (size_t)(n * 1024 + t) * 3072 + h * 64;
    float q[64], o[64];
#pragma unroll
    for (int i = 0; i < 8; i++) {
        bf16x8 v8 = *(const bf16x8*)(qrow + i * 8);
#pragma unroll
        for (int jj = 0; jj < 8; jj++) { q[i * 8 + jj] = (float)v8[jj]; o[i * 8 + jj] = 0.f; }
    }
    float m = -1e30f, lsum = 0.f;
    const bf16_t* kb = qkv + (size_t)n * 1024 * 3072 + 1024 + h * 64 + (size_t)(wave * 256) * 3072;
    for (int s = 0; s < 256; s++) {
        const bf16_t* kr = kb + (size_t)s * 3072;
        float dot = 0.f;
#pragma unroll
        for (int i = 0; i < 8; i++) {
            bf16x8 k8 = *(const bf16x8*)(kr + i * 8);
#pragma unroll
            for (int jj = 0; jj < 8; jj++) dot += q[i * 8 + jj] * (float)k8[jj];
        }
        dot *= 0.125f;                  // 1/sqrt(64)
        float mn = fmaxf(m, dot);
        float al = __expf(m - mn);
        float p  = __expf(dot - mn);
        lsum = lsum * al + p;
        const bf16_t* vr = kr + 1024;   // v section
#pragma unroll
        for (int i = 0; i < 8; i++) {
            bf16x8 v8 = *(const bf16x8*)(vr + i * 8);
#pragma unroll
            for (int jj = 0; jj < 8; jj++) o[i * 8 + jj] = o[i * 8 + jj] * al + p * (float)v8[jj];
        }
        m = mn;
    }
    sm[wave][lane] = m;
    sl[wave][lane] = lsum;
#pragma unroll
    for (int i = 0; i < 64; i++) so[wave][lane][i] = (bf16_t)o[i];
    __syncthreads();
    const int qq = tid >> 2, seg = tid & 3;
    float m0 = sm[0][qq], m1 = sm[1][qq], m2 = sm[2][qq], m3 = sm[3][qq];
    float M = fmaxf(fmaxf(m0, m1), fmaxf(m2, m3));
    float w0 = __expf(m0 - M), w1 = __expf(m1 - M), w2 = __expf(m2 - M), w3 = __expf(m3 - M);
    float L = sl[0][qq] * w0 + sl[1][qq] * w1 + sl[2][qq] * w2 + sl[3][qq] * w3;
    float inv = 1.f / L;
    const int tq = qb * 64 + qq;
    bf16_t* op = obuf + (size_t)(n * 1024 + tq) * 1024 + h * 64 + seg * 16;
#pragma unroll
    for (int d = 0; d < 16; d++) {
        int dd = seg * 16 + d;
        float val = (float)so[0][qq][dd] * w0 + (float)so[1][qq][dd] * w1 +
                    (float)so[2][qq][dd] * w2 + (float)so[3][qq][dd] * w3;
        op[d] = (bf16_t)(val * inv);
    }
}

// ---------------- final rmsnorm scale per token ----------------
__global__ __launch_bounds__(256) void rmsscale_k(const float* __restrict__ tok, float* __restrict__ scale)
{
    int row = blockIdx.x, tid = threadIdx.x;
    float4 xv = ((const float4*)(tok + (size_t)row * 1024))[tid];
    float s = xv.x * xv.x + xv.y * xv.y + xv.z * xv.z + xv.w * xv.w;
#pragma unroll
    for (int off = 32; off > 0; off >>= 1) s += __shfl_down(s, off, 64);
    __shared__ float ws4[4];
    if ((tid & 63) == 0) ws4[tid >> 6] = s;
    __syncthreads();
    if (tid == 0)
        scale[row] = rsqrtf((ws4[0] + ws4[1] + ws4[2] + ws4[3]) * (1.f / 1024.f) + 1e-6f);
}

// ---------------- scale + transpose: out f32 [n][d][t] = tok[n][t][d]*scale[n,t] ----------------
__global__ __launch_bounds__(256) void transpose_out_k(const float* __restrict__ tok,
                                                       const float* __restrict__ scale,
                                                       float* __restrict__ out)
{
    __shared__ float tile[64][65];
    const int tid = threadIdx.x;
    const int tt = blockIdx.x * 64, dd = blockIdx.y * 64, n = blockIdx.z;
#pragma unroll
    for (int rb = 0; rb < 4; rb++) {
        int tl = rb * 16 + (tid >> 4);
        int cl = (tid & 15) * 4;
        float4 v = *(const float4*)(tok + (size_t)(n * 1024 + tt + tl) * 1024 + dd + cl);
        float sc = scale[n * 1024 + tt + tl];
        tile[cl + 0][tl] = v.x * sc;
        tile[cl + 1][tl] = v.y * sc;
        tile[cl + 2][tl] = v.z * sc;
        tile[cl + 3][tl] = v.w * sc;
    }
    __syncthreads();
#pragma unroll
    for (int rb = 0; rb < 4; rb++) {
        int dl = rb * 16 + (tid >> 4);
        int tl = (tid & 15) * 4;
        float4 v = make_float4(tile[dl][tl + 0], tile[dl][tl + 1], tile[dl][tl + 2], tile[dl][tl + 3]);
        *(float4*)(out + (size_t)n * 1024 * 1024 + (size_t)(dd + dl) * 1024 + tt + tl) = v;
    }
}

extern "C" void kernel_launch(void* const* d_in, const int* in_sizes, int n_in,
                              void* d_out, int out_size, void* d_ws, size_t ws_size,
                              hipStream_t stream)
{
    // All inputs are float32 per the reference's setup_inputs().
    const float* x       = (const float*)d_in[0];
    const float* merge_w = (const float*)d_in[1];
    const float* qkv_w   = (const float*)d_in[2];
    const float* qkv_b   = (const float*)d_in[3];
    const float* proj_w  = (const float*)d_in[4];
    const float* proj_b  = (const float*)d_in[5];
    const float* fc1_w   = (const float*)d_in[6];
    const float* fc1_b   = (const float*)d_in[7];
    const float* fc2_w   = (const float*)d_in[8];
    const float* fc2_b   = (const float*)d_in[9];
    float* out = (float*)d_out;

    // Workspace (~92 MB):
    char* ws = (char*)d_ws;
    float*  tok   = (float*)ws;                          // 16 MB  [0,16)
    bf16_t* Ab    = (bf16_t*)(ws + (16u << 20));         //  8 MB  [16,24)
    bf16_t* ob    = (bf16_t*)(ws + (24u << 20));         //  8 MB  [24,32)
    bf16_t* qkvb  = (bf16_t*)(ws + (32u << 20));         // 24 MB  [32,56) (dead after attn)
    bf16_t* hid   = (bf16_t*)(ws + (32u << 20));         // 32 MB  [32,64) (live fc1->fc2)
    bf16_t* wqkv  = (bf16_t*)(ws + (64u << 20));         // 6.29 MB
    bf16_t* wproj = wqkv + (size_t)3072 * 1024;          // 2.10 MB
    bf16_t* wfc1  = wproj + (size_t)1024 * 1024;         // 8.39 MB
    bf16_t* wfc2  = wfc1 + (size_t)4096 * 1024;          // 8.39 MB  (ends ~89.2 MB)
    bf16_t* wmrg  = (bf16_t*)(ws + (90u << 20));         // 128 KB
    float*  scl   = (float*)(ws + (91u << 20));          // 16 KB

    cvt_k<<<64, 256, 0, stream>>>(merge_w, wmrg);        // 65536 els
    patches_k<<<1024, 256, 0, stream>>>(x, Ab);
    gemm128<0><<<dim3(32, 8), 256, 0, stream>>>(Ab, wmrg, nullptr, tok, nullptr, 1024, 64);

    for (int i = 0; i < 8; i++) {
        convw_k<<<12288, 256, 0, stream>>>(
            qkv_w + (size_t)i * 3072 * 1024, proj_w + (size_t)i * 1024 * 1024,
            fc1_w + (size_t)i * 4096 * 1024, fc2_w + (size_t)i * 1024 * 4096,
            wqkv, wproj, wfc1, wfc2);

        rmsnorm_k<<<4096, 256, 0, stream>>>(tok, Ab);
        gemm128<4><<<dim3(32, 24), 256, 0, stream>>>(Ab, wqkv, qkv_b + (size_t)i * 3072,
                                                     nullptr, qkvb, 3072, 1024);
        rope_k<<<8192, 256, 0, stream>>>(qkvb);
        attn_k<<<1024, 256, 0, stream>>>(qkvb, ob);
        gemm128<2><<<dim3(32, 8), 256, 0, stream>>>(ob, wproj, proj_b + (size_t)i * 1024,
                                                    tok, nullptr, 1024, 1024);
        rmsnorm_k<<<4096, 256, 0, stream>>>(tok, Ab);
        gemm128<3><<<dim3(32, 32), 256, 0, stream>>>(Ab, wfc1, fc1_b + (size_t)i * 4096,
                                                     nullptr, hid, 4096, 1024);
        gemm128<2><<<dim3(32, 8), 256, 0, stream>>>(hid, wfc2, fc2_b + (size_t)i * 1024,
                                                    tok, nullptr, 1024, 4096);
    }
    rmsscale_k<<<4096, 256, 0, stream>>>(tok, scl);
    transpose_out_k<<<dim3(16, 16, 4), 256, 0, stream>>>(tok, scl, out);
}